// Round 5
// baseline (72.772 us; speedup 1.0000x reference)
//
#include <hip/hip_runtime.h>

#define HH 160
#define WW 160
#define HW (HH*WW)
#define NB 16
#define NM 64
#define NC 43
#define BLKX 100                 // blocks per image (256 px each)
#define NBLK (NB*BLKX)           // 1600 total blocks
#define CELLBASE NBLK            // part[] layout: [0,1600) heat, [1600,1600+2048) cells

constexpr float STRIDE = 4.0f;   // 640 / 160
constexpr float EPSF = 1e-7f;
constexpr float BIGF = 3.4e38f;

// Shared geometry: must be bit-identical everywhere it is evaluated.
__device__ __forceinline__ void box_geom(const float* __restrict__ bb,
                                         const int* __restrict__ labels, int tid,
                                         bool& valid, int& gx, int& gy,
                                         float& cx, float& cy, float& bw, float& bh) {
  float x1 = bb[tid * 4 + 0], y1 = bb[tid * 4 + 1];
  float x2 = bb[tid * 4 + 2], y2 = bb[tid * 4 + 3];
  cx = (x1 + x2) * 0.5f;
  cy = (y1 + y2) * 0.5f;
  bw = x2 - x1;
  bh = y2 - y1;
  int lab = labels[tid];
  valid = (lab >= 0) && ((x1 + y1 + x2 + y2) > 0.0f) && (bw > 0.0f) && (bh > 0.0f);
  int tgx = (int)(cx * 0.25f);            // /4 exact; trunc matches astype(int32)
  int tgy = (int)(cy * 0.25f);
  gx = tgx < 0 ? 0 : (tgx > WW - 1 ? WW - 1 : tgx);
  gy = tgy < 0 ? 0 : (tgy > HH - 1 ? HH - 1 : tgy);
}

// One kernel: heat focal (all blocks) + winner-cell losses (bx<32) + last-block finalize.
__global__ __launch_bounds__(128) void k_all(const float* __restrict__ pred_heat,
                                             const float* __restrict__ pred_boxes,
                                             const float* __restrict__ pred_classes,
                                             const float* __restrict__ bboxes,
                                             const int* __restrict__ labels,
                                             float2* __restrict__ part,
                                             unsigned int* __restrict__ ticket,
                                             float* __restrict__ out) {
  __shared__ float4 sp[NM];                // (z, -2z*gx, -2z*gy, z*(gx^2+gy^2) | NaN)
  __shared__ float lred[2];
  __shared__ int nred[2];
  __shared__ int islast;
  __shared__ double fin[2][6];

  int b = blockIdx.y, bx = blockIdx.x;
  int tid = threadIdx.x;
  int wave = tid >> 6, lane = tid & 63;

  if (tid < NM) {
    int t = b * NM + tid;
    bool valid; int gx, gy; float cx, cy, bw, bh;
    box_geom(bboxes, labels, t, valid, gx, gy, cx, cy, bw, bh);
    float rf = fmaxf(sqrtf(bw * bh) * 0.25f, 2.0f);   // fmax(NaN,2)=2 for junk boxes
    float r = (float)(int)rf;
    float z = 2.0f / (r * r);              // 1/(2*sigma^2); covered iff a <= 8
    float gxf = (float)gx, gyf = (float)gy;
    float4 p;
    p.x = z;
    p.y = -2.0f * z * gxf;
    p.z = -2.0f * z * gyf;
    p.w = valid ? z * fmaf(gxf, gxf, gyf * gyf) : __int_as_float(0x7fc00000);
    sp[tid] = p;                           // NaN K => a=NaN => v_min_f32 skips (IEEE)
  }
  __syncthreads();

  // ---- heat: 2 px/thread, polynomial distance ----
  int pixbase = bx * 256 + tid * 2;        // within image; pair never crosses a row
  int idx = b * HW + pixbase;
  float2 pr = *(const float2*)(pred_heat + idx);
  float xf0 = (float)(pixbase % WW);
  float yf = (float)(pixbase / WW);
  float xf1 = xf0 + 1.0f;
  float s0 = fmaf(xf0, xf0, yf * yf);
  float s1 = fmaf(xf1, xf1, yf * yf);

  float m00 = BIGF, m01 = BIGF, m10 = BIGF, m11 = BIGF;
  #pragma unroll
  for (int m = 0; m < NM; m += 2) {
    float4 c0 = sp[m], c1 = sp[m + 1];
    { float base = fmaf(c0.z, yf, c0.w);
      m00 = fminf(m00, fmaf(c0.x, s0, fmaf(c0.y, xf0, base)));
      m01 = fminf(m01, fmaf(c0.x, s1, fmaf(c0.y, xf1, base))); }
    { float base = fmaf(c1.z, yf, c1.w);
      m10 = fminf(m10, fmaf(c1.x, s0, fmaf(c1.y, xf0, base)));
      m11 = fminf(m11, fmaf(c1.x, s1, fmaf(c1.y, xf1, base))); }
  }
  float mina0 = fminf(m00, m10);
  float mina1 = fminf(m01, m11);

  float t0 = (mina0 <= 8.0f) ? __expf(-mina0) : 0.0f;
  float t1 = (mina1 <= 8.0f) ? __expf(-mina1) : 0.0f;
  float p0 = fminf(fmaxf(pr.x, EPSF), 1.0f - EPSF);
  float p1 = fminf(fmaxf(pr.y, EPSF), 1.0f - EPSF);
  float q0 = 1.0f - p0, q1 = 1.0f - p1;
  bool pos0 = t0 > 0.5f, pos1 = t1 > 0.5f;
  float lg0 = __logf(pos0 ? p0 : q0);
  float lg1 = __logf(pos1 ? p1 : q1);
  float cf0 = pos0 ? (-0.25f * q0 * q0 * t0) : (-0.75f * p0 * p0 * (1.0f - t0));
  float cf1 = pos1 ? (-0.25f * q1 * q1 * t1) : (-0.75f * p1 * p1 * (1.0f - t1));
  float loss = fmaf(cf0, lg0, cf1 * lg1);

  // num_pos via ballot (no int shuffle chain); f32 loss reduce (1 bpermute/step)
  int cnt = __popcll(__ballot(pos0)) + __popcll(__ballot(pos1));
  #pragma unroll
  for (int off = 32; off > 0; off >>= 1) loss += __shfl_down(loss, off);
  if (lane == 0) { lred[wave] = loss; nred[wave] = cnt; }
  __syncthreads();
  if (tid == 0)
    part[b * BLKX + bx] = make_float2(lred[0] + lred[1], (float)(nred[0] + nred[1]));

  // ---- cells: waves of blocks bx<32 each own box m = bx*2+wave of image b ----
  if (bx < 32) {
    int m = bx * 2 + wave;        // 0..63
    int lbox = b * NM + lane;
    bool valid; int gx, gy; float cx, cy, bw, bh;
    box_geom(bboxes, labels, lbox, valid, gx, gy, cx, cy, bw, bh);
    int lab = labels[lbox]; lab = lab < 0 ? 0 : (lab > NC - 1 ? NC - 1 : lab);

    int   valid_m = __shfl((int)valid, m);
    int   gx_m = __shfl(gx, m), gy_m = __shfl(gy, m);
    float cx_m = __shfl(cx, m), cy_m = __shfl(cy, m);
    float bw_m = __shfl(bw, m), bh_m = __shfl(bh, m);

    float l1 = 0.0f, csum = 0.0f;
    int cnt1 = 0, npos = 0;
    if (valid_m) {
      bool maps = valid && (gx == gx_m) && (gy == gy_m);
      unsigned long long mk = __ballot(maps);         // valid boxes on this cell
      if ((63 - __clzll(mk)) == m) {                  // highest m wins == atomicMax
        unsigned long long cm = maps ? (1ull << lab) : 0ull;
        #pragma unroll
        for (int o = 1; o < 64; o <<= 1) cm |= __shfl_xor(cm, o);
        int celloff = gy_m * WW + gx_m;
        if (lane == 0) {
          float dxv = (cx_m - ((float)gx_m + 0.5f) * STRIDE) * 0.25f;
          float dyv = (cy_m - ((float)gy_m + 0.5f) * STRIDE) * 0.25f;
          float dwv = __logf(bw_m * 0.25f + 1e-6f);
          float dhv = __logf(bh_m * 0.25f + 1e-6f);
          const float* pb = pred_boxes + (size_t)b * 4 * HW + celloff;
          l1 = fabsf(pb[0] - dxv) + fabsf(pb[HW] - dyv) +
               fabsf(pb[2 * HW] - dwv) + fabsf(pb[3 * HW] - dhv);
          cnt1 = 1;
          npos = __popcll(cm);
        }
        if (lane < NC) {
          float x = pred_classes[(size_t)b * NC * HW + (size_t)lane * HW + celloff];
          float s = 1.0f / (1.0f + __expf(-x));
          float pc = fminf(fmaxf(s, EPSF), 1.0f - EPSF);
          float omc = 1.0f - pc;
          csum = ((cm >> lane) & 1ull) ? (-0.25f * omc * omc * __logf(pc))
                                       : (-0.75f * pc * pc * __logf(omc));
        }
        #pragma unroll
        for (int o = 32; o > 0; o >>= 1) csum += __shfl_down(csum, o);
      }
    }
    if (lane == 0) {
      int w = b * NM + m;
      part[CELLBASE + 2 * w]     = make_float2(l1, (float)cnt1);
      part[CELLBASE + 2 * w + 1] = make_float2(csum, (float)npos);
    }
  }

  // ---- ticket: last block finalizes ----
  __threadfence();                          // release: partials visible device-wide
  if (tid == 0) {
    unsigned int old = atomicAdd(ticket, 1u);
    islast = (old == NBLK - 1) ? 1 : 0;
  }
  __syncthreads();
  if (!islast) return;
  __threadfence();                          // acquire: invalidate stale L1/L2

  double hs = 0.0, l1 = 0.0, cs = 0.0, hc = 0.0, mc = 0.0, cp = 0.0;
  for (int i = tid; i < NBLK; i += 128) {
    float2 v = part[i];
    hs += (double)v.x; hc += (double)v.y;
  }
  for (int i = tid; i < NB * NM; i += 128) {
    float2 e0 = part[CELLBASE + 2 * i];
    float2 e1 = part[CELLBASE + 2 * i + 1];
    l1 += (double)e0.x; mc += (double)e0.y;
    cs += (double)e1.x; cp += (double)e1.y;
  }
  #pragma unroll
  for (int off = 32; off > 0; off >>= 1) {
    hs += __shfl_down(hs, off); hc += __shfl_down(hc, off);
    l1 += __shfl_down(l1, off); mc += __shfl_down(mc, off);
    cs += __shfl_down(cs, off); cp += __shfl_down(cp, off);
  }
  if (lane == 0) {
    fin[wave][0] = hs; fin[wave][1] = hc; fin[wave][2] = l1;
    fin[wave][3] = mc; fin[wave][4] = cs; fin[wave][5] = cp;
  }
  __syncthreads();
  if (tid == 0) {
    double HS = fin[0][0] + fin[1][0];
    double HC = fin[0][1] + fin[1][1];
    double L1 = fin[0][2] + fin[1][2];
    double MC = fin[0][3] + fin[1][3];
    double CS = fin[0][4] + fin[1][4];
    double CP = fin[0][5] + fin[1][5];
    double nph = HC < 1.0 ? 1.0 : HC;
    float heat = (float)(HS / nph);
    float box = 0.0f, cls = 0.0f;
    if (MC > 1.5) {                         // MC integral: num_pos > 1
      box = (float)(L1 / MC);
      double c = CP < 1.0 ? 1.0 : CP;
      cls = (float)(CS / c);
    }
    out[0] = heat + box + cls;
  }
}

extern "C" void kernel_launch(void* const* d_in, const int* in_sizes, int n_in,
                              void* d_out, int out_size, void* d_ws, size_t ws_size,
                              hipStream_t stream) {
  const float* pred_heat    = (const float*)d_in[0];   // (16,1,160,160)
  const float* pred_boxes   = (const float*)d_in[1];   // (16,4,160,160)
  const float* pred_classes = (const float*)d_in[2];   // (16,43,160,160)
  const float* bboxes       = (const float*)d_in[3];   // (16,64,4)
  const int*   labels       = (const int*)d_in[4];     // (16,64)

  char* ws = (char*)d_ws;
  unsigned int* ticket = (unsigned int*)ws;            // 4 B, zeroed every call
  float2* part = (float2*)(ws + 64);                   // (1600 + 2048) float2 = 29184 B

  hipMemsetAsync(ticket, 0, 4, stream);
  dim3 grid(BLKX, NB);
  k_all<<<grid, 128, 0, stream>>>(pred_heat, pred_boxes, pred_classes,
                                  bboxes, labels, part, ticket, (float*)d_out);
}

// Round 6
// 14.872 us; speedup vs baseline: 4.8931x; 4.8931x over previous
//
#include <hip/hip_runtime.h>

#define HH 160
#define WW 160
#define HW (HH*WW)
#define NB 16
#define NM 64
#define NC 43
#define BLKX 50                  // blocks per image, 512 px each (128 thr x 4 px)
#define NBLK (NB*BLKX)           // 800 heat partials
#define CELLBASE NBLK            // part[]: [0,800) heat, [800, 800+2048) cells

constexpr float STRIDE = 4.0f;   // 640 / 160
constexpr float EPSF = 1e-7f;
constexpr float BIGF = 3.4e38f;

// Shared geometry: must be bit-identical everywhere it is evaluated.
__device__ __forceinline__ void box_geom(const float* __restrict__ bb,
                                         const int* __restrict__ labels, int tid,
                                         bool& valid, int& gx, int& gy,
                                         float& cx, float& cy, float& bw, float& bh) {
  float x1 = bb[tid * 4 + 0], y1 = bb[tid * 4 + 1];
  float x2 = bb[tid * 4 + 2], y2 = bb[tid * 4 + 3];
  cx = (x1 + x2) * 0.5f;
  cy = (y1 + y2) * 0.5f;
  bw = x2 - x1;
  bh = y2 - y1;
  int lab = labels[tid];
  valid = (lab >= 0) && ((x1 + y1 + x2 + y2) > 0.0f) && (bw > 0.0f) && (bh > 0.0f);
  int tgx = (int)(cx * 0.25f);            // /4 exact; trunc matches astype(int32)
  int tgy = (int)(cy * 0.25f);
  gx = tgx < 0 ? 0 : (tgx > WW - 1 ? WW - 1 : tgx);
  gy = tgy < 0 ? 0 : (tgy > HH - 1 ? HH - 1 : tgy);
}

// Heat focal (all blocks, 4 px/thread, polynomial distance) +
// winner-cell losses (bx<32, one wave per box, ballot ownership). NO fences/atomics.
__global__ __launch_bounds__(128) void k_fused(const float* __restrict__ pred_heat,
                                               const float* __restrict__ pred_boxes,
                                               const float* __restrict__ pred_classes,
                                               const float* __restrict__ bboxes,
                                               const int* __restrict__ labels,
                                               float2* __restrict__ part) {
  __shared__ float4 sp[NM];                // (z, -2z*gx, -2z*gy, z*(gx^2+gy^2) | NaN)
  __shared__ float lred[2];
  __shared__ int nred[2];

  int b = blockIdx.y, bx = blockIdx.x;
  int tid = threadIdx.x;
  int wave = tid >> 6, lane = tid & 63;

  if (tid < NM) {
    int t = b * NM + tid;
    bool valid; int gx, gy; float cx, cy, bw, bh;
    box_geom(bboxes, labels, t, valid, gx, gy, cx, cy, bw, bh);
    float rf = fmaxf(sqrtf(bw * bh) * 0.25f, 2.0f);   // fmax(NaN,2)=2 for junk boxes
    float r = (float)(int)rf;
    float z = 2.0f / (r * r);              // 1/(2*sigma^2); covered iff a <= 8
    float gxf = (float)gx, gyf = (float)gy;
    float4 p;
    p.x = z;
    p.y = -2.0f * z * gxf;
    p.z = -2.0f * z * gyf;
    p.w = valid ? z * fmaf(gxf, gxf, gyf * gyf) : __int_as_float(0x7fc00000);
    sp[tid] = p;                           // NaN K => a=NaN => v_min_f32 skips (IEEE)
  }
  __syncthreads();

  // ---- heat: 4 px/thread (always same row: 512 & 160 are multiples of 4) ----
  int pixbase = bx * 512 + tid * 4;        // within image
  int idx = b * HW + pixbase;
  float4 pr4 = *(const float4*)(pred_heat + idx);    // coalesced 16B, issued early
  int row = pixbase / WW;
  float xf0 = (float)(pixbase - row * WW);
  float yf = (float)row;
  float xf1 = xf0 + 1.0f, xf2 = xf0 + 2.0f, xf3 = xf0 + 3.0f;
  float yy = yf * yf;
  float s0 = fmaf(xf0, xf0, yy), s1 = fmaf(xf1, xf1, yy);
  float s2 = fmaf(xf2, xf2, yy), s3 = fmaf(xf3, xf3, yy);

  // a = z*s + zcx*x + zcy*y + K ; one fmin chain per pixel (4-way ILP)
  float m0 = BIGF, m1 = BIGF, m2 = BIGF, m3 = BIGF;
  #pragma unroll
  for (int m = 0; m < NM; m += 2) {
    float4 c0 = sp[m], c1 = sp[m + 1];
    { float base = fmaf(c0.z, yf, c0.w);
      m0 = fminf(m0, fmaf(c0.x, s0, fmaf(c0.y, xf0, base)));
      m1 = fminf(m1, fmaf(c0.x, s1, fmaf(c0.y, xf1, base)));
      m2 = fminf(m2, fmaf(c0.x, s2, fmaf(c0.y, xf2, base)));
      m3 = fminf(m3, fmaf(c0.x, s3, fmaf(c0.y, xf3, base))); }
    { float base = fmaf(c1.z, yf, c1.w);
      m0 = fminf(m0, fmaf(c1.x, s0, fmaf(c1.y, xf0, base)));
      m1 = fminf(m1, fmaf(c1.x, s1, fmaf(c1.y, xf1, base)));
      m2 = fminf(m2, fmaf(c1.x, s2, fmaf(c1.y, xf2, base)));
      m3 = fminf(m3, fmaf(c1.x, s3, fmaf(c1.y, xf3, base))); }
  }

  float t0 = (m0 <= 8.0f) ? __expf(-m0) : 0.0f;
  float t1 = (m1 <= 8.0f) ? __expf(-m1) : 0.0f;
  float t2 = (m2 <= 8.0f) ? __expf(-m2) : 0.0f;
  float t3 = (m3 <= 8.0f) ? __expf(-m3) : 0.0f;
  float p0 = fminf(fmaxf(pr4.x, EPSF), 1.0f - EPSF);
  float p1 = fminf(fmaxf(pr4.y, EPSF), 1.0f - EPSF);
  float p2 = fminf(fmaxf(pr4.z, EPSF), 1.0f - EPSF);
  float p3 = fminf(fmaxf(pr4.w, EPSF), 1.0f - EPSF);
  float q0 = 1.0f - p0, q1 = 1.0f - p1, q2 = 1.0f - p2, q3 = 1.0f - p3;
  bool o0 = t0 > 0.5f, o1 = t1 > 0.5f, o2 = t2 > 0.5f, o3 = t3 > 0.5f;
  float lg0 = __logf(o0 ? p0 : q0), lg1 = __logf(o1 ? p1 : q1);
  float lg2 = __logf(o2 ? p2 : q2), lg3 = __logf(o3 ? p3 : q3);
  float cf0 = o0 ? (-0.25f * q0 * q0 * t0) : (-0.75f * p0 * p0 * (1.0f - t0));
  float cf1 = o1 ? (-0.25f * q1 * q1 * t1) : (-0.75f * p1 * p1 * (1.0f - t1));
  float cf2 = o2 ? (-0.25f * q2 * q2 * t2) : (-0.75f * p2 * p2 * (1.0f - t2));
  float cf3 = o3 ? (-0.25f * q3 * q3 * t3) : (-0.75f * p3 * p3 * (1.0f - t3));
  float loss = fmaf(cf0, lg0, cf1 * lg1) + fmaf(cf2, lg2, cf3 * lg3);

  int cnt = __popcll(__ballot(o0)) + __popcll(__ballot(o1)) +
            __popcll(__ballot(o2)) + __popcll(__ballot(o3));
  #pragma unroll
  for (int off = 32; off > 0; off >>= 1) loss += __shfl_down(loss, off);
  if (lane == 0) { lred[wave] = loss; nred[wave] = cnt; }
  __syncthreads();
  if (tid == 0)
    part[b * BLKX + bx] = make_float2(lred[0] + lred[1], (float)(nred[0] + nred[1]));

  // ---- cells: waves of blocks bx<32 each own box m = bx*2+wave of image b ----
  if (bx < 32) {
    int m = bx * 2 + wave;        // 0..63
    int lbox = b * NM + lane;
    bool valid; int gx, gy; float cx, cy, bw, bh;
    box_geom(bboxes, labels, lbox, valid, gx, gy, cx, cy, bw, bh);
    int lab = labels[lbox]; lab = lab < 0 ? 0 : (lab > NC - 1 ? NC - 1 : lab);

    int   valid_m = __shfl((int)valid, m);
    int   gx_m = __shfl(gx, m), gy_m = __shfl(gy, m);
    float cx_m = __shfl(cx, m), cy_m = __shfl(cy, m);
    float bw_m = __shfl(bw, m), bh_m = __shfl(bh, m);

    float l1 = 0.0f, csum = 0.0f;
    int cnt1 = 0, npos = 0;
    if (valid_m) {
      bool maps = valid && (gx == gx_m) && (gy == gy_m);
      unsigned long long mk = __ballot(maps);         // valid boxes on this cell
      if ((63 - __clzll(mk)) == m) {                  // highest m wins == atomicMax
        unsigned long long cm = maps ? (1ull << lab) : 0ull;
        #pragma unroll
        for (int o = 1; o < 64; o <<= 1) cm |= __shfl_xor(cm, o);
        int celloff = gy_m * WW + gx_m;
        if (lane == 0) {
          float dxv = (cx_m - ((float)gx_m + 0.5f) * STRIDE) * 0.25f;
          float dyv = (cy_m - ((float)gy_m + 0.5f) * STRIDE) * 0.25f;
          float dwv = __logf(bw_m * 0.25f + 1e-6f);
          float dhv = __logf(bh_m * 0.25f + 1e-6f);
          const float* pb = pred_boxes + (size_t)b * 4 * HW + celloff;
          l1 = fabsf(pb[0] - dxv) + fabsf(pb[HW] - dyv) +
               fabsf(pb[2 * HW] - dwv) + fabsf(pb[3 * HW] - dhv);
          cnt1 = 1;
          npos = __popcll(cm);
        }
        if (lane < NC) {
          float x = pred_classes[(size_t)b * NC * HW + (size_t)lane * HW + celloff];
          float s = 1.0f / (1.0f + __expf(-x));
          float pc = fminf(fmaxf(s, EPSF), 1.0f - EPSF);
          float omc = 1.0f - pc;
          csum = ((cm >> lane) & 1ull) ? (-0.25f * omc * omc * __logf(pc))
                                       : (-0.75f * pc * pc * __logf(omc));
        }
        #pragma unroll
        for (int o = 32; o > 0; o >>= 1) csum += __shfl_down(csum, o);
      }
    }
    if (lane == 0) {
      int w = b * NM + m;
      part[CELLBASE + 2 * w]     = make_float2(l1, (float)cnt1);
      part[CELLBASE + 2 * w + 1] = make_float2(csum, (float)npos);
    }
  }
}

// Single-block tree reduce of all partials + finalize.
__global__ __launch_bounds__(256) void k_final(const float2* __restrict__ part,
                                               float* __restrict__ out) {
  int t = threadIdx.x;
  double hs = 0.0, hc = 0.0, l1 = 0.0, mc = 0.0, cs = 0.0, cp = 0.0;
  for (int i = t; i < NBLK; i += 256) {
    float2 v = part[i];
    hs += (double)v.x; hc += (double)v.y;
  }
  for (int i = t; i < NB * NM; i += 256) {
    float2 e0 = part[CELLBASE + 2 * i];
    float2 e1 = part[CELLBASE + 2 * i + 1];
    l1 += (double)e0.x; mc += (double)e0.y;
    cs += (double)e1.x; cp += (double)e1.y;
  }
  #pragma unroll
  for (int off = 32; off > 0; off >>= 1) {
    hs += __shfl_down(hs, off); hc += __shfl_down(hc, off);
    l1 += __shfl_down(l1, off); mc += __shfl_down(mc, off);
    cs += __shfl_down(cs, off); cp += __shfl_down(cp, off);
  }
  __shared__ double fin[4][6];
  int wave = t >> 6;
  if ((t & 63) == 0) {
    fin[wave][0] = hs; fin[wave][1] = hc; fin[wave][2] = l1;
    fin[wave][3] = mc; fin[wave][4] = cs; fin[wave][5] = cp;
  }
  __syncthreads();
  if (t == 0) {
    double HS = 0, HC = 0, L1 = 0, MC = 0, CS = 0, CP = 0;
    for (int i = 0; i < 4; ++i) {
      HS += fin[i][0]; HC += fin[i][1]; L1 += fin[i][2];
      MC += fin[i][3]; CS += fin[i][4]; CP += fin[i][5];
    }
    double nph = HC < 1.0 ? 1.0 : HC;
    float heat = (float)(HS / nph);
    float box = 0.0f, cls = 0.0f;
    if (MC > 1.5) {                         // MC integral: num_pos > 1
      box = (float)(L1 / MC);
      double c = CP < 1.0 ? 1.0 : CP;
      cls = (float)(CS / c);
    }
    out[0] = heat + box + cls;
  }
}

extern "C" void kernel_launch(void* const* d_in, const int* in_sizes, int n_in,
                              void* d_out, int out_size, void* d_ws, size_t ws_size,
                              hipStream_t stream) {
  const float* pred_heat    = (const float*)d_in[0];   // (16,1,160,160)
  const float* pred_boxes   = (const float*)d_in[1];   // (16,4,160,160)
  const float* pred_classes = (const float*)d_in[2];   // (16,43,160,160)
  const float* bboxes       = (const float*)d_in[3];   // (16,64,4)
  const int*   labels       = (const int*)d_in[4];     // (16,64)

  float2* part = (float2*)d_ws;            // (800 + 2048) float2 = 22784 B

  dim3 grid(BLKX, NB);
  k_fused<<<grid, 128, 0, stream>>>(pred_heat, pred_boxes, pred_classes,
                                    bboxes, labels, part);
  k_final<<<1, 256, 0, stream>>>(part, (float*)d_out);
}